// Round 1
// baseline (1188.836 us; speedup 1.0000x reference)
//
#include <hip/hip_runtime.h>
#include <math.h>

#define NPTS 4096
#define BLK 256
#define NPROJ 256
#define NBATCH 32

__global__ __launch_bounds__(BLK) void swd_kernel(
    const float* __restrict__ x, const float* __restrict__ y,
    const float* __restrict__ theta, const float* __restrict__ rot,
    float* __restrict__ per_batch) {
    __shared__ float xs[NPTS];
    __shared__ float ys[NPTS];

    const int p = blockIdx.x;
    const int b = blockIdx.y;

    // proj[e] = sum_d theta[p,d] * rot[b,d,e]
    const float t0 = theta[p * 3 + 0], t1 = theta[p * 3 + 1], t2 = theta[p * 3 + 2];
    const float* R = rot + b * 9;
    const float p0 = t0 * R[0] + t1 * R[3] + t2 * R[6];
    const float p1 = t0 * R[1] + t1 * R[4] + t2 * R[7];
    const float p2 = t0 * R[2] + t1 * R[5] + t2 * R[8];

    const float* xb = x + (size_t)b * NPTS * 3;
    const float* yb = y + (size_t)b * NPTS * 3;

    for (int i = threadIdx.x; i < NPTS; i += BLK) {
        xs[i] = xb[i * 3 + 0] * p0 + xb[i * 3 + 1] * p1 + xb[i * 3 + 2] * p2;
        ys[i] = yb[i * 3 + 0] * p0 + yb[i * 3 + 1] * p1 + yb[i * 3 + 2] * p2;
    }

    // Bitonic sort both arrays in LDS (ascending).
    for (int k = 2; k <= NPTS; k <<= 1) {
        for (int j = k >> 1; j > 0; j >>= 1) {
            __syncthreads();
            for (int t = threadIdx.x; t < NPTS / 2; t += BLK) {
                const int i = ((t & ~(j - 1)) << 1) | (t & (j - 1));
                const int ixj = i | j;
                const bool asc = ((i & k) == 0);
                float a = xs[i], c = xs[ixj];
                if ((a > c) == asc) { xs[i] = c; xs[ixj] = a; }
                float e = ys[i], f = ys[ixj];
                if ((e > f) == asc) { ys[i] = f; ys[ixj] = e; }
            }
        }
    }
    __syncthreads();

    // Sum of squared differences of the sorted arrays.
    float s = 0.0f;
    for (int i = threadIdx.x; i < NPTS; i += BLK) {
        const float d = xs[i] - ys[i];
        s += d * d;
    }

    // Wave reduce (wave = 64 lanes), then cross-wave via LDS.
    for (int off = 32; off > 0; off >>= 1) s += __shfl_down(s, off, 64);
    __shared__ float wsum[BLK / 64];
    const int lane = threadIdx.x & 63;
    const int wave = threadIdx.x >> 6;
    if (lane == 0) wsum[wave] = s;
    __syncthreads();
    if (threadIdx.x == 0) {
        float tot = 0.0f;
        for (int w = 0; w < BLK / 64; ++w) tot += wsum[w];
        atomicAdd(&per_batch[b], tot);
    }
}

__global__ void finalize_kernel(const float* __restrict__ per_batch, float* __restrict__ out) {
    const int t = threadIdx.x;  // 64 threads
    float v = (t < NBATCH) ? sqrtf(per_batch[t] * (1.0f / (float)NPROJ)) : 0.0f;
    for (int off = 32; off > 0; off >>= 1) v += __shfl_down(v, off, 64);
    if (t == 0) out[0] = v * (1.0f / (float)NBATCH);
}

extern "C" void kernel_launch(void* const* d_in, const int* in_sizes, int n_in,
                              void* d_out, int out_size, void* d_ws, size_t ws_size,
                              hipStream_t stream) {
    const float* x = (const float*)d_in[0];
    const float* y = (const float*)d_in[1];
    const float* theta = (const float*)d_in[2];
    const float* rot = (const float*)d_in[3];
    float* per_batch = (float*)d_ws;
    float* out = (float*)d_out;

    hipMemsetAsync(per_batch, 0, NBATCH * sizeof(float), stream);

    dim3 grid(NPROJ, NBATCH);
    swd_kernel<<<grid, BLK, 0, stream>>>(x, y, theta, rot, per_batch);

    finalize_kernel<<<1, 64, 0, stream>>>(per_batch, out);
}

// Round 2
// 410.622 us; speedup vs baseline: 2.8952x; 2.8952x over previous
//
#include <hip/hip_runtime.h>
#include <math.h>

#define NPTS 4096
#define BLK 256
#define V 16
#define NPROJ 256
#define NBATCH 32

// XOR-swizzle LDS addressing: permutes bits [7:4] by bits [11:8].
// Keeps L-layout 16-float blocks contiguous (float4-able) while making
// M/H strided access <=2-way bank aliased (free on gfx950).
__device__ __forceinline__ int sw(int idx) {
    return idx ^ (((idx >> 8) & 15) << 4);
}

__device__ __forceinline__ void cmpex(float& a, float& b, bool asc) {
    float lo = fminf(a, b), hi = fmaxf(a, b);
    a = asc ? lo : hi;
    b = asc ? hi : lo;
}

// Execute bitonic stages j = JB<<SHIFT down to 1<<SHIFT, entirely in registers.
// rest = global-index bits contributed by the thread (register bits zero).
template<int K, int SHIFT, int JB>
__device__ __forceinline__ void stages_down(float* vx, float* vy, int rest) {
#pragma unroll
    for (int r = 0; r < V; ++r) {
        if ((r & JB) == 0) {
            const bool asc = (((rest | (r << SHIFT)) & K) == 0);
            cmpex(vx[r], vx[r | JB], asc);
            cmpex(vy[r], vy[r | JB], asc);
        }
    }
    if constexpr (JB > 1) stages_down<K, SHIFT, (JB >> 1)>(vx, vy, rest);
}

// L layout: thread t owns idx bits [3:0]; idx = (t<<4)|r  (contiguous, float4)
__device__ __forceinline__ void writeL(float* s, const float* v, int t) {
    float4* s4 = (float4*)(s + sw(t << 4));
#pragma unroll
    for (int q = 0; q < 4; ++q)
        s4[q] = make_float4(v[4 * q], v[4 * q + 1], v[4 * q + 2], v[4 * q + 3]);
}
__device__ __forceinline__ void readL(const float* s, float* v, int t) {
    const float4* s4 = (const float4*)(s + sw(t << 4));
#pragma unroll
    for (int q = 0; q < 4; ++q) {
        float4 f = s4[q];
        v[4 * q] = f.x; v[4 * q + 1] = f.y; v[4 * q + 2] = f.z; v[4 * q + 3] = f.w;
    }
}
// M layout: thread owns idx bits [7:4]; idx = ((t>>4)<<8)|(r<<4)|(t&15)
__device__ __forceinline__ void writeM(float* s, const float* v, int restM) {
#pragma unroll
    for (int r = 0; r < V; ++r) s[sw(restM | (r << 4))] = v[r];
}
__device__ __forceinline__ void readM(const float* s, float* v, int restM) {
#pragma unroll
    for (int r = 0; r < V; ++r) v[r] = s[sw(restM | (r << 4))];
}
// H layout: thread owns idx bits [11:8]; idx = (r<<8)|t
__device__ __forceinline__ void writeH(float* s, const float* v, int t) {
#pragma unroll
    for (int r = 0; r < V; ++r) s[sw((r << 8) | t)] = v[r];
}
__device__ __forceinline__ void readH(const float* s, float* v, int t) {
#pragma unroll
    for (int r = 0; r < V; ++r) v[r] = s[sw((r << 8) | t)];
}

#define REMAP(WR, RD, AW, AR)                          \
    WR(xs, vx, AW); WR(ys, vy, AW); __syncthreads();   \
    RD(xs, vx, AR); RD(ys, vy, AR); __syncthreads();

__global__ __launch_bounds__(BLK) void swd_kernel(
    const float* __restrict__ x, const float* __restrict__ y,
    const float* __restrict__ theta, const float* __restrict__ rot,
    float* __restrict__ per_batch) {
    __shared__ float xs[NPTS];
    __shared__ float ys[NPTS];

    const int t = threadIdx.x;
    const int p = blockIdx.x;
    const int b = blockIdx.y;

    // proj[e] = sum_d theta[p,d] * rot[b,d,e]
    const float t0 = theta[p * 3 + 0], t1 = theta[p * 3 + 1], t2 = theta[p * 3 + 2];
    const float* R = rot + b * 9;
    const float p0 = t0 * R[0] + t1 * R[3] + t2 * R[6];
    const float p1 = t0 * R[1] + t1 * R[4] + t2 * R[7];
    const float p2 = t0 * R[2] + t1 * R[5] + t2 * R[8];

    // Load 16 points of each array (L layout: global idx = t*16+r), project.
    float vx[V], vy[V];
    {
        const float4* xb4 = (const float4*)(x + (size_t)b * NPTS * 3 + (size_t)t * V * 3);
        const float4* yb4 = (const float4*)(y + (size_t)b * NPTS * 3 + (size_t)t * V * 3);
#pragma unroll
        for (int g = 0; g < 4; ++g) {
            float4 a = xb4[g * 3 + 0], c = xb4[g * 3 + 1], d = xb4[g * 3 + 2];
            vx[4 * g + 0] = a.x * p0 + a.y * p1 + a.z * p2;
            vx[4 * g + 1] = a.w * p0 + c.x * p1 + c.y * p2;
            vx[4 * g + 2] = c.z * p0 + c.w * p1 + d.x * p2;
            vx[4 * g + 3] = d.y * p0 + d.z * p1 + d.w * p2;
            a = yb4[g * 3 + 0]; c = yb4[g * 3 + 1]; d = yb4[g * 3 + 2];
            vy[4 * g + 0] = a.x * p0 + a.y * p1 + a.z * p2;
            vy[4 * g + 1] = a.w * p0 + c.x * p1 + c.y * p2;
            vy[4 * g + 2] = c.z * p0 + c.w * p1 + d.x * p2;
            vy[4 * g + 3] = d.y * p0 + d.z * p1 + d.w * p2;
        }
    }

    const int restL = t << 4;
    const int restM = ((t >> 4) << 8) | (t & 15);

    // Phase 1: k = 2..16, all inside thread-owned bits (no barriers).
    stages_down<2, 0, 1>(vx, vy, restL);
    stages_down<4, 0, 2>(vx, vy, restL);
    stages_down<8, 0, 4>(vx, vy, restL);
    stages_down<16, 0, 8>(vx, vy, restL);

    // k = 32..256: high stages in M layout, low stages in L layout.
    REMAP(writeL, readM, t, restM);
    stages_down<32, 4, 1>(vx, vy, restM);
    REMAP(writeM, readL, restM, t);
    stages_down<32, 0, 8>(vx, vy, restL);

    REMAP(writeL, readM, t, restM);
    stages_down<64, 4, 2>(vx, vy, restM);
    REMAP(writeM, readL, restM, t);
    stages_down<64, 0, 8>(vx, vy, restL);

    REMAP(writeL, readM, t, restM);
    stages_down<128, 4, 4>(vx, vy, restM);
    REMAP(writeM, readL, restM, t);
    stages_down<128, 0, 8>(vx, vy, restL);

    REMAP(writeL, readM, t, restM);
    stages_down<256, 4, 8>(vx, vy, restM);
    REMAP(writeM, readL, restM, t);
    stages_down<256, 0, 8>(vx, vy, restL);

    // k = 512..4096: H stages, then M stages, then L stages.
    REMAP(writeL, readH, t, t);
    stages_down<512, 8, 1>(vx, vy, t);
    REMAP(writeH, readM, t, restM);
    stages_down<512, 4, 8>(vx, vy, restM);
    REMAP(writeM, readL, restM, t);
    stages_down<512, 0, 8>(vx, vy, restL);

    REMAP(writeL, readH, t, t);
    stages_down<1024, 8, 2>(vx, vy, t);
    REMAP(writeH, readM, t, restM);
    stages_down<1024, 4, 8>(vx, vy, restM);
    REMAP(writeM, readL, restM, t);
    stages_down<1024, 0, 8>(vx, vy, restL);

    REMAP(writeL, readH, t, t);
    stages_down<2048, 8, 4>(vx, vy, t);
    REMAP(writeH, readM, t, restM);
    stages_down<2048, 4, 8>(vx, vy, restM);
    REMAP(writeM, readL, restM, t);
    stages_down<2048, 0, 8>(vx, vy, restL);

    REMAP(writeL, readH, t, t);
    stages_down<4096, 8, 8>(vx, vy, t);
    REMAP(writeH, readM, t, restM);
    stages_down<4096, 4, 8>(vx, vy, restM);
    REMAP(writeM, readL, restM, t);
    stages_down<4096, 0, 8>(vx, vy, restL);

    // Sorted ascending in L layout. Sum squared differences.
    float s = 0.0f;
#pragma unroll
    for (int r = 0; r < V; ++r) {
        const float d = vx[r] - vy[r];
        s += d * d;
    }

    // Wave reduce, cross-wave via (now-free) xs, one atomic per block.
    for (int off = 32; off > 0; off >>= 1) s += __shfl_down(s, off, 64);
    const int lane = t & 63;
    const int wave = t >> 6;
    if (lane == 0) xs[wave] = s;
    __syncthreads();
    if (t == 0) {
        float tot = xs[0] + xs[1] + xs[2] + xs[3];
        atomicAdd(&per_batch[b], tot);
    }
}

__global__ void finalize_kernel(const float* __restrict__ per_batch, float* __restrict__ out) {
    const int t = threadIdx.x;  // 64 threads
    float v = (t < NBATCH) ? sqrtf(per_batch[t] * (1.0f / (float)NPROJ)) : 0.0f;
    for (int off = 32; off > 0; off >>= 1) v += __shfl_down(v, off, 64);
    if (t == 0) out[0] = v * (1.0f / (float)NBATCH);
}

extern "C" void kernel_launch(void* const* d_in, const int* in_sizes, int n_in,
                              void* d_out, int out_size, void* d_ws, size_t ws_size,
                              hipStream_t stream) {
    const float* x = (const float*)d_in[0];
    const float* y = (const float*)d_in[1];
    const float* theta = (const float*)d_in[2];
    const float* rot = (const float*)d_in[3];
    float* per_batch = (float*)d_ws;
    float* out = (float*)d_out;

    hipMemsetAsync(per_batch, 0, NBATCH * sizeof(float), stream);

    dim3 grid(NPROJ, NBATCH);
    swd_kernel<<<grid, BLK, 0, stream>>>(x, y, theta, rot, per_batch);

    finalize_kernel<<<1, 64, 0, stream>>>(per_batch, out);
}

// Round 3
// 408.537 us; speedup vs baseline: 2.9100x; 1.0051x over previous
//
#include <hip/hip_runtime.h>
#include <math.h>

#define NPTS 4096
#define BLK 256
#define V 16
#define NPROJ 256
#define NBATCH 32

// LDS placement: element with global index idx lives at float address
//   phi(idx) = idx ^ (((idx>>8)&3)<<2) ^ (((idx>>9)&1)<<4)
// Verified: L accesses (16 consecutive idx/thread, float4) span all 32 banks
// (8 dwords/bank per b128 = optimal); M (stride-16) and H (stride-256) are
// <=2-way (free on gfx950). All layouts address via precomputed bases +
// compile-time offsets: zero per-access VALU.

__device__ __forceinline__ void cmpex(float& a, float& b, bool asc) {
    float lo = fminf(a, b), hi = fmaxf(a, b);
    a = asc ? lo : hi;
    b = asc ? hi : lo;
}

// Execute bitonic stages j = JB<<SHIFT down to 1<<SHIFT, entirely in registers.
// rest = global-index bits contributed by the thread (register bits zero).
template<int K, int SHIFT, int JB>
__device__ __forceinline__ void stages_down(float* vx, float* vy, int rest) {
#pragma unroll
    for (int r = 0; r < V; ++r) {
        if ((r & JB) == 0) {
            const bool asc = (((rest | (r << SHIFT)) & K) == 0);
            cmpex(vx[r], vx[r | JB], asc);
            cmpex(vy[r], vy[r | JB], asc);
        }
    }
    if constexpr (JB > 1) stages_down<K, SHIFT, (JB >> 1)>(vx, vy, rest);
}

// L layout: thread owns idx = (t<<4)|r. Address: float4 base (t^t5b)<<2,
// quad slot q ^ t54 (bits [3:2] of phi), registers natural.
__device__ __forceinline__ void writeL(float* s, const float* v, int fb4, int t54) {
    float4* p4 = (float4*)s + fb4;
#pragma unroll
    for (int q = 0; q < 4; ++q)
        p4[q ^ t54] = make_float4(v[4 * q], v[4 * q + 1], v[4 * q + 2], v[4 * q + 3]);
}
__device__ __forceinline__ void readL(const float* s, float* v, int fb4, int t54) {
    const float4* p4 = (const float4*)s + fb4;
#pragma unroll
    for (int q = 0; q < 4; ++q) {
        float4 f = p4[q ^ t54];
        v[4 * q] = f.x; v[4 * q + 1] = f.y; v[4 * q + 2] = f.z; v[4 * q + 3] = f.w;
    }
}
// M layout: thread owns idx = (t74<<8)|(r<<4)|t30. Address = base +/-
// (t5b<<4) for even/odd slots + r*16 floats (compile-time imm offsets).
__device__ __forceinline__ void writeM(float* se, float* so, const float* v) {
#pragma unroll
    for (int r = 0; r < V; ++r) {
        if (r & 1) so[r * 16] = v[r]; else se[r * 16] = v[r];
    }
}
__device__ __forceinline__ void readM(const float* se, const float* so, float* v) {
#pragma unroll
    for (int r = 0; r < V; ++r) {
        v[r] = (r & 1) ? so[r * 16] : se[r * 16];
    }
}
// H layout: thread owns idx = (r<<8)|t. Four bases selected by r&3 at
// unroll time; offset r<<8 floats.
__device__ __forceinline__ void writeH(float* s, const float* v,
                                       int b0, int b1, int b2, int b3) {
#pragma unroll
    for (int r = 0; r < V; ++r) {
        const int bh = ((r & 3) == 0) ? b0 : ((r & 3) == 1) ? b1 : ((r & 3) == 2) ? b2 : b3;
        s[(r << 8) + bh] = v[r];
    }
}
__device__ __forceinline__ void readH(const float* s, float* v,
                                      int b0, int b1, int b2, int b3) {
#pragma unroll
    for (int r = 0; r < V; ++r) {
        const int bh = ((r & 3) == 0) ? b0 : ((r & 3) == 1) ? b1 : ((r & 3) == 2) ? b2 : b3;
        v[r] = s[(r << 8) + bh];
    }
}

__global__ __launch_bounds__(BLK) void swd_kernel(
    const float* __restrict__ x, const float* __restrict__ y,
    const float* __restrict__ theta, const float* __restrict__ rot,
    float* __restrict__ per_batch) {
    __shared__ float xs[NPTS];
    __shared__ float ys[NPTS];

    const int t = threadIdx.x;
    const int p = blockIdx.x;
    const int b = blockIdx.y;

    // proj[e] = sum_d theta[p,d] * rot[b,d,e]
    const float t0 = theta[p * 3 + 0], t1 = theta[p * 3 + 1], t2 = theta[p * 3 + 2];
    const float* R = rot + b * 9;
    const float p0 = t0 * R[0] + t1 * R[3] + t2 * R[6];
    const float p1 = t0 * R[1] + t1 * R[4] + t2 * R[7];
    const float p2 = t0 * R[2] + t1 * R[5] + t2 * R[8];

    // Load 16 points of each array (L layout: global idx = t*16+r), project.
    float vx[V], vy[V];
    {
        const float4* xb4 = (const float4*)(x + (size_t)b * NPTS * 3 + (size_t)t * V * 3);
        const float4* yb4 = (const float4*)(y + (size_t)b * NPTS * 3 + (size_t)t * V * 3);
#pragma unroll
        for (int g = 0; g < 4; ++g) {
            float4 a = xb4[g * 3 + 0], c = xb4[g * 3 + 1], d = xb4[g * 3 + 2];
            vx[4 * g + 0] = a.x * p0 + a.y * p1 + a.z * p2;
            vx[4 * g + 1] = a.w * p0 + c.x * p1 + c.y * p2;
            vx[4 * g + 2] = c.z * p0 + c.w * p1 + d.x * p2;
            vx[4 * g + 3] = d.y * p0 + d.z * p1 + d.w * p2;
            a = yb4[g * 3 + 0]; c = yb4[g * 3 + 1]; d = yb4[g * 3 + 2];
            vy[4 * g + 0] = a.x * p0 + a.y * p1 + a.z * p2;
            vy[4 * g + 1] = a.w * p0 + c.x * p1 + c.y * p2;
            vy[4 * g + 2] = c.z * p0 + c.w * p1 + d.x * p2;
            vy[4 * g + 3] = d.y * p0 + d.z * p1 + d.w * p2;
        }
    }

    // Precomputed addressing (see phi above).
    const int t5b = (t >> 5) & 1;
    const int t54 = (t >> 4) & 3;
    const int fb4 = (t ^ t5b) << 2;                    // L float4 base
    const int t74 = t >> 4, t30 = t & 15;
    const int baseM = (t74 << 8) | (t30 ^ (t54 << 2)); // M float base
    const int bME = baseM + (t5b << 4);
    const int bMO = baseM - (t5b << 4);
    const int bH0 = t;                                 // H bases, c = r&3
    const int bH1 = t ^ 4;
    const int bH2 = t ^ 8 ^ 16;
    const int bH3 = t ^ 12 ^ 16;

    const int restL = t << 4;
    const int restM = (t74 << 8) | t30;

#define WRL writeL(xs, vx, fb4, t54); writeL(ys, vy, fb4, t54);
#define RDL readL(xs, vx, fb4, t54); readL(ys, vy, fb4, t54);
#define WRM writeM(xs + bME, xs + bMO, vx); writeM(ys + bME, ys + bMO, vy);
#define RDM readM(xs + bME, xs + bMO, vx); readM(ys + bME, ys + bMO, vy);
#define WRH writeH(xs, vx, bH0, bH1, bH2, bH3); writeH(ys, vy, bH0, bH1, bH2, bH3);
#define RDH readH(xs, vx, bH0, bH1, bH2, bH3); readH(ys, vy, bH0, bH1, bH2, bH3);
#define SYNC __syncthreads();

    // Phase 1: k = 2..16, all inside thread-owned bits (no barriers).
    stages_down<2, 0, 1>(vx, vy, restL);
    stages_down<4, 0, 2>(vx, vy, restL);
    stages_down<8, 0, 4>(vx, vy, restL);
    stages_down<16, 0, 8>(vx, vy, restL);

    // k = 32..256: high stages in M layout, low stages in L layout.
    WRL SYNC RDM SYNC
    stages_down<32, 4, 1>(vx, vy, restM);
    WRM SYNC RDL SYNC
    stages_down<32, 0, 8>(vx, vy, restL);

    WRL SYNC RDM SYNC
    stages_down<64, 4, 2>(vx, vy, restM);
    WRM SYNC RDL SYNC
    stages_down<64, 0, 8>(vx, vy, restL);

    WRL SYNC RDM SYNC
    stages_down<128, 4, 4>(vx, vy, restM);
    WRM SYNC RDL SYNC
    stages_down<128, 0, 8>(vx, vy, restL);

    WRL SYNC RDM SYNC
    stages_down<256, 4, 8>(vx, vy, restM);
    WRM SYNC RDL SYNC
    stages_down<256, 0, 8>(vx, vy, restL);

    // k = 512..4096: H stages, then M stages, then L stages.
    WRL SYNC RDH SYNC
    stages_down<512, 8, 1>(vx, vy, t);
    WRH SYNC RDM SYNC
    stages_down<512, 4, 8>(vx, vy, restM);
    WRM SYNC RDL SYNC
    stages_down<512, 0, 8>(vx, vy, restL);

    WRL SYNC RDH SYNC
    stages_down<1024, 8, 2>(vx, vy, t);
    WRH SYNC RDM SYNC
    stages_down<1024, 4, 8>(vx, vy, restM);
    WRM SYNC RDL SYNC
    stages_down<1024, 0, 8>(vx, vy, restL);

    WRL SYNC RDH SYNC
    stages_down<2048, 8, 4>(vx, vy, t);
    WRH SYNC RDM SYNC
    stages_down<2048, 4, 8>(vx, vy, restM);
    WRM SYNC RDL SYNC
    stages_down<2048, 0, 8>(vx, vy, restL);

    WRL SYNC RDH SYNC
    stages_down<4096, 8, 8>(vx, vy, t);
    WRH SYNC RDM SYNC
    stages_down<4096, 4, 8>(vx, vy, restM);
    WRM SYNC RDL SYNC
    stages_down<4096, 0, 8>(vx, vy, restL);

    // Sorted ascending. Sum squared differences.
    float s = 0.0f;
#pragma unroll
    for (int r = 0; r < V; ++r) {
        const float d = vx[r] - vy[r];
        s += d * d;
    }

    // Wave reduce, cross-wave via (now-free) xs, one atomic per block.
    for (int off = 32; off > 0; off >>= 1) s += __shfl_down(s, off, 64);
    const int lane = t & 63;
    const int wave = t >> 6;
    if (lane == 0) xs[wave] = s;
    __syncthreads();
    if (t == 0) {
        float tot = xs[0] + xs[1] + xs[2] + xs[3];
        atomicAdd(&per_batch[b], tot);
    }
}

__global__ void finalize_kernel(const float* __restrict__ per_batch, float* __restrict__ out) {
    const int t = threadIdx.x;  // 64 threads
    float v = (t < NBATCH) ? sqrtf(per_batch[t] * (1.0f / (float)NPROJ)) : 0.0f;
    for (int off = 32; off > 0; off >>= 1) v += __shfl_down(v, off, 64);
    if (t == 0) out[0] = v * (1.0f / (float)NBATCH);
}

extern "C" void kernel_launch(void* const* d_in, const int* in_sizes, int n_in,
                              void* d_out, int out_size, void* d_ws, size_t ws_size,
                              hipStream_t stream) {
    const float* x = (const float*)d_in[0];
    const float* y = (const float*)d_in[1];
    const float* theta = (const float*)d_in[2];
    const float* rot = (const float*)d_in[3];
    float* per_batch = (float*)d_ws;
    float* out = (float*)d_out;

    hipMemsetAsync(per_batch, 0, NBATCH * sizeof(float), stream);

    dim3 grid(NPROJ, NBATCH);
    swd_kernel<<<grid, BLK, 0, stream>>>(x, y, theta, rot, per_batch);

    finalize_kernel<<<1, 64, 0, stream>>>(per_batch, out);
}